// Round 3
// baseline (305.687 us; speedup 1.0000x reference)
//
#include <hip/hip_runtime.h>
#include <stdint.h>

// MFMA fragment types (gfx950)
typedef __attribute__((ext_vector_type(8))) short short8;  // 8 bf16 = 4 VGPRs
typedef __attribute__((ext_vector_type(4))) float f32x4;   // 4 fp32 acc / vec load

static_assert(sizeof(short8) == 16, "frag size");

__device__ __forceinline__ uint16_t f2bf(float f) {
  uint32_t u = __builtin_bit_cast(uint32_t, f);
  u += 0x7fffu + ((u >> 16) & 1u);
  return (uint16_t)(u >> 16);
}

__device__ __forceinline__ short8 pack_bf16x8(f32x4 lo, f32x4 hi) {
  union { uint32_t u[4]; short8 s; } z;
  z.u[0] = (uint32_t)f2bf(lo.x) | ((uint32_t)f2bf(lo.y) << 16);
  z.u[1] = (uint32_t)f2bf(lo.z) | ((uint32_t)f2bf(lo.w) << 16);
  z.u[2] = (uint32_t)f2bf(hi.x) | ((uint32_t)f2bf(hi.y) << 16);
  z.u[3] = (uint32_t)f2bf(hi.z) | ((uint32_t)f2bf(hi.w) << 16);
  return z.s;
}

__device__ __forceinline__ void gload_lds16(const void* g, void* lds_wave_base) {
  // async global->LDS, 16B/lane; LDS dst = wave-uniform base + lane*16
  __builtin_amdgcn_global_load_lds(
      (__attribute__((address_space(1))) void*)(void*)(g),
      (__attribute__((address_space(3))) void*)(lds_wave_base),
      16, 0, 0);
}

// ---------------------------------------------------------------------------
// quant: dwT[o][i] = ternary(weight[i][o]) in {-1,0,+1} bf16, swizzled
// (swizzle feeds support_kernel's B-DMA path only).
// ---------------------------------------------------------------------------
__global__ __launch_bounds__(256) void quant_kernel(const float* __restrict__ w,
                                                    uint16_t* __restrict__ dwT) {
  const int o = blockIdx.x, i = threadIdx.x;
  const float v = w[i * 256 + o];
  const float t = (v > 0.01f) ? 1.0f : ((v < -0.01f) ? -1.0f : 0.0f);
  dwT[o * 256 + (i ^ ((o & 7) << 3))] = f2bf(t);
}

// ---------------------------------------------------------------------------
// support (SINGLE-PASS K=256): spt[o][g] = bf16(0.01 * sum_i x[g][i]*tern[i][o])
// Tile [64 g][64 o], full K staged once (A 32 KB + B 32 KB = 64 KB LDS,
// 2 blocks/CU). Grid 1024 = 256 g-tiles x 4 o-tiles.
// NOTE (R3): spt is now stored LINEAR (un-swizzled at copy-out) because the
// main kernel reads B fragments directly from global memory.
// ---------------------------------------------------------------------------
#define SB_A 0       // [64 g][256 i] bf16 swizzled, 32768 B (reused in epilogue)
#define SB_B 32768   // [64 o][256 i] bf16 swizzled, 32768 B

__global__ __launch_bounds__(256) void support_kernel(const float* __restrict__ x,
                                                      const uint16_t* __restrict__ dwT,
                                                      uint16_t* __restrict__ spt) {
  __shared__ __align__(16) unsigned char smem[65536];
  const int t = threadIdx.x, lane = t & 63, w = t >> 6;
  const int r = lane & 15, q = lane >> 4;
  const int g0 = (blockIdx.x & 255) * 64;
  const int o0 = (blockIdx.x >> 8) * 64;

  // stage A: x [64 g][256 i] fp32 -> bf16, packed b128 swizzled writes
#pragma unroll
  for (int j = 0; j < 8; ++j) {
    const int id = j * 256 + t;              // 64 rows x 32 chunks = 2048 ids
    const int row = id >> 5, c = id & 31;
    const float* p = x + (size_t)(g0 + row) * 256 + c * 8;
    const f32x4 v0 = *(const f32x4*)p;
    const f32x4 v1 = *(const f32x4*)(p + 4);
    uint4 u;
    u.x = (uint32_t)f2bf(v0.x) | ((uint32_t)f2bf(v0.y) << 16);
    u.y = (uint32_t)f2bf(v0.z) | ((uint32_t)f2bf(v0.w) << 16);
    u.z = (uint32_t)f2bf(v1.x) | ((uint32_t)f2bf(v1.y) << 16);
    u.w = (uint32_t)f2bf(v1.z) | ((uint32_t)f2bf(v1.w) << 16);
    *(uint4*)(smem + SB_A + row * 512 + ((c ^ (row & 7)) << 4)) = u;
  }
  // stage B: dwT rows [o0,o0+64) full K, verbatim DMA (pre-swizzled)
#pragma unroll
  for (int j = 0; j < 8; ++j) {
    const int id = j * 256 + t, row = id >> 5, c = id & 31;
    gload_lds16(dwT + (size_t)(o0 + row) * 256 + c * 8,
                smem + SB_B + (size_t)(j * 256 + w * 64) * 16);
  }
  __syncthreads();

  f32x4 acc[4] = {};
#pragma unroll
  for (int h = 0; h < 8; ++h) {              // K=256 in 8 steps of 32
    short8 av, bv[4];
    const int pc = (((h * 4 + q) ^ (r & 7)) << 4);
    av = *(const short8*)(smem + SB_A + (16 * w + r) * 512 + pc);
#pragma unroll
    for (int ni = 0; ni < 4; ++ni)
      bv[ni] = *(const short8*)(smem + SB_B + (16 * ni + r) * 512 + pc);
#pragma unroll
    for (int ni = 0; ni < 4; ++ni)
      acc[ni] = __builtin_amdgcn_mfma_f32_16x16x32_bf16(av, bv[ni], acc[ni], 0, 0, 0);
  }
  __syncthreads();   // all waves' LDS reads done before transpose overwrite

  // epilogue: transpose buffer [64 o][64 g] bf16 (8 KB, reuses SB_A region).
  // LDS writes stay swizzled (conflict-free); copy-out un-swizzles so that
  // GLOBAL spt is linear.
#pragma unroll
  for (int ni = 0; ni < 4; ++ni) {
    const int ol = 16 * ni + r;              // C col = o
#pragma unroll
    for (int reg = 0; reg < 4; ++reg) {
      const int gl = 16 * w + 4 * q + reg;   // C row = g
      const int gsw = gl ^ ((ol & 7) << 3);  // LDS-local swizzle only
      *(uint16_t*)(smem + (ol * 64 + gsw) * 2) = f2bf(acc[ni][reg] * 0.01f);
    }
  }
  __syncthreads();
  // copy out: 64 rows x 8 chunks of 16 B, un-swizzled, coalesced dwordx4
#pragma unroll
  for (int it = 0; it < 2; ++it) {
    const int id = it * 256 + t, row = id >> 3, cc = id & 7;
    const uint4 u = *(const uint4*)(smem + (row * 64 + ((cc ^ (row & 7)) * 8)) * 2);
    *(uint4*)(spt + (size_t)(o0 + row) * 16384 + g0 + cc * 8) = u;
  }
}

// ---------------------------------------------------------------------------
// main v4 (LDS-FREE, BARRIER-FREE direct-fragment streaming):
//   out = relu(adj @ support + bias)
// R2 counters: 79.7us, hbm 11%, MfmaUtil 8%, VALU 11%, occ 19% -> pure
// barrier-locked latency. Fix per Common-mistake #7: B (spt, 1 MB/batch) is
// L2-resident; A (adj) frags are 32B-contiguous per lane, shared only by the
// 4 waves of one block (L1). MFMA frag layouts are directly global-loadable:
//   A frag lane(r,q): adj row n0+16*mi+r, k = kc+q*8 .. +8  (8 fp32, 32 B)
//   B frag lane(r,q): spt row ob+16*ni+r, k = kc+q*8 .. +8  (8 bf16, 16 B)
// Each wave owns [32 n][64 o], streams K=2048 in 32-elem chunks with a
// depth-2 register pipeline (sets X/Y, statically named per rule #20).
// No LDS, no barriers: 8 independent waves/CU, loads stay in flight across
// the whole body (~2 chunks ~ 1600 cyc > 900 cyc HBM latency).
// ---------------------------------------------------------------------------
__global__ __launch_bounds__(256, 3) void gcn_main_kernel(const float* __restrict__ adj,
                                                          const uint16_t* __restrict__ spt,
                                                          const float* __restrict__ bias,
                                                          float* __restrict__ out) {
  const int t = threadIdx.x, lane = t & 63, w = t >> 6;
  const int r = lane & 15, q = lane >> 4;
  const int bb = blockIdx.x & 7;             // batch -> XCD affinity (spt[bb] L2-resident)
  const int n0 = (blockIdx.x >> 3) * 32;     // n-tile
  const int ob = w * 64;                     // wave's o-base
  const float* adjb = adj + ((size_t)bb * 2048 + n0) * 2048;
  const uint16_t* sptb = spt + (size_t)bb * 2048;

  // per-lane fragment base pointers
  const float* aR0 = adjb + (size_t)r * 2048 + q * 8;         // mi=0 rows
  const float* aR1 = adjb + (size_t)(r + 16) * 2048 + q * 8;  // mi=1 rows
  const uint16_t* bR0 = sptb + (size_t)(ob + r) * 16384 + q * 8;
  const uint16_t* bR1 = bR0 + (size_t)16 * 16384;
  const uint16_t* bR2 = bR0 + (size_t)32 * 16384;
  const uint16_t* bR3 = bR0 + (size_t)48 * 16384;

  f32x4 acc[2][4] = {};

#define LOAD_SET(A0, A1, A2, A3, B0, B1, B2, B3, KO)                           \
  do {                                                                         \
    A0 = *(const f32x4*)(aR0 + (KO));                                          \
    A1 = *(const f32x4*)(aR0 + (KO) + 4);                                      \
    A2 = *(const f32x4*)(aR1 + (KO));                                          \
    A3 = *(const f32x4*)(aR1 + (KO) + 4);                                      \
    B0 = *(const short8*)(bR0 + (KO));                                         \
    B1 = *(const short8*)(bR1 + (KO));                                         \
    B2 = *(const short8*)(bR2 + (KO));                                         \
    B3 = *(const short8*)(bR3 + (KO));                                         \
  } while (0)

#define COMPUTE_SET(A0, A1, A2, A3, B0, B1, B2, B3)                            \
  do {                                                                         \
    const short8 av0 = pack_bf16x8(A0, A1);                                    \
    const short8 av1 = pack_bf16x8(A2, A3);                                    \
    acc[0][0] = __builtin_amdgcn_mfma_f32_16x16x32_bf16(av0, B0, acc[0][0], 0, 0, 0); \
    acc[0][1] = __builtin_amdgcn_mfma_f32_16x16x32_bf16(av0, B1, acc[0][1], 0, 0, 0); \
    acc[0][2] = __builtin_amdgcn_mfma_f32_16x16x32_bf16(av0, B2, acc[0][2], 0, 0, 0); \
    acc[0][3] = __builtin_amdgcn_mfma_f32_16x16x32_bf16(av0, B3, acc[0][3], 0, 0, 0); \
    acc[1][0] = __builtin_amdgcn_mfma_f32_16x16x32_bf16(av1, B0, acc[1][0], 0, 0, 0); \
    acc[1][1] = __builtin_amdgcn_mfma_f32_16x16x32_bf16(av1, B1, acc[1][1], 0, 0, 0); \
    acc[1][2] = __builtin_amdgcn_mfma_f32_16x16x32_bf16(av1, B2, acc[1][2], 0, 0, 0); \
    acc[1][3] = __builtin_amdgcn_mfma_f32_16x16x32_bf16(av1, B3, acc[1][3], 0, 0, 0); \
  } while (0)

  // depth-2 pipeline: set X = chunk kt, set Y = chunk kt+32
  f32x4 xa0, xa1, xa2, xa3; short8 xb0, xb1, xb2, xb3;
  f32x4 ya0, ya1, ya2, ya3; short8 yb0, yb1, yb2, yb3;
  LOAD_SET(xa0, xa1, xa2, xa3, xb0, xb1, xb2, xb3, 0);
  LOAD_SET(ya0, ya1, ya2, ya3, yb0, yb1, yb2, yb3, 32);

  for (int kt = 0; kt < 2048; kt += 64) {
    COMPUTE_SET(xa0, xa1, xa2, xa3, xb0, xb1, xb2, xb3);
    if (kt + 64 < 2048)
      LOAD_SET(xa0, xa1, xa2, xa3, xb0, xb1, xb2, xb3, kt + 64);
    COMPUTE_SET(ya0, ya1, ya2, ya3, yb0, yb1, yb2, yb3);
    if (kt + 96 < 2048)
      LOAD_SET(ya0, ya1, ya2, ya3, yb0, yb1, yb2, yb3, kt + 96);
  }

  // epilogue: +bias, relu, fp32 store
#pragma unroll
  for (int ni = 0; ni < 4; ++ni) {
    const int o = ob + 16 * ni + r;          // C col = N = o
    const float bs = bias[o];
#pragma unroll
    for (int mi = 0; mi < 2; ++mi)
#pragma unroll
      for (int reg = 0; reg < 4; ++reg) {
        const int n = n0 + 16 * mi + 4 * q + reg;  // C row = M = n
        out[((size_t)bb * 2048 + n) * 256 + o] = fmaxf(acc[mi][ni][reg] + bs, 0.0f);
      }
  }
#undef LOAD_SET
#undef COMPUTE_SET
}

// ---------------------------------------------------------------------------
extern "C" void kernel_launch(void* const* d_in, const int* in_sizes, int n_in,
                              void* d_out, int out_size, void* d_ws, size_t ws_size,
                              hipStream_t stream) {
  const float* x      = (const float*)d_in[0];  // [8,2048,256]
  const float* adj    = (const float*)d_in[1];  // [8,2048,2048]
  const float* weight = (const float*)d_in[2];  // [256,256]
  const float* bias   = (const float*)d_in[3];  // [256]
  float* out = (float*)d_out;                   // [8,2048,256]

  uint16_t* dwT = (uint16_t*)d_ws;                          // 128 KB
  uint16_t* spt = (uint16_t*)((char*)d_ws + 131072);        // 8 MB

  hipLaunchKernelGGL(quant_kernel,    dim3(256),  dim3(256), 0, stream, weight, dwT);
  hipLaunchKernelGGL(support_kernel,  dim3(1024), dim3(256), 0, stream, x, dwT, spt);
  hipLaunchKernelGGL(gcn_main_kernel, dim3(512),  dim3(256), 0, stream, adj, spt, bias, out);
}